// Round 1
// baseline (591.393 us; speedup 1.0000x reference)
//
#include <hip/hip_runtime.h>
#include <math.h>

// Problem: N=8192 fp32. out = r_inv[:,None] * (a*b + I), r_inv = 1/rowsum(a*b+I), inf->0.
// One block per row: 256 threads x 8 float4 = 8192 floats = one full row.
//
// R1 changes vs baseline (191 us/dispatch, 2.8 TB/s HBM):
//  - VGPR_Count=24 proved the compiler REMATERIALIZED prod[] after the barrier
//    (re-load a,b from L2 + recompute): 40 vmem ops/thread instead of 24.
//    Pin products in VGPRs with an empty asm keep-alive -> post-barrier phase
//    is a pure store burst.
//  - Drop the 2nd __syncthreads: every thread sums the 4 wave partials itself.
//  - Non-temporal stores: output is streamed-once; don't evict the LLC lines
//    currently absorbing ~256 MB/dispatch of input fetches.

#define NDIM 8192
#define BLOCK 256
#define V4_PER_THREAD (NDIM / 4 / BLOCK)   // 8

typedef float f32x4 __attribute__((ext_vector_type(4)));

__global__ __launch_bounds__(BLOCK) void row_normalize_kernel(
    const float* __restrict__ a,
    const float* __restrict__ b,
    float* __restrict__ out)
{
    const int row = blockIdx.x;
    const int tid = threadIdx.x;

    const float4* __restrict__ a4 = (const float4*)(a + (size_t)row * NDIM);
    const float4* __restrict__ b4 = (const float4*)(b + (size_t)row * NDIM);
    float*       __restrict__ orow = out + (size_t)row * NDIM;

    float4 prod[V4_PER_THREAD];
    double sum = 0.0;

#pragma unroll
    for (int i = 0; i < V4_PER_THREAD; ++i) {
        const int idx = tid + i * BLOCK;          // coalesced: lane stride 16B
        const float4 av = a4[idx];
        const float4 bv = b4[idx];
        float4 p;
        p.x = av.x * bv.x;
        p.y = av.y * bv.y;
        p.z = av.z * bv.z;
        p.w = av.w * bv.w;
        // identity: mx[row][row] += 1
        const int col0 = idx << 2;
        if ((unsigned)(row - col0) < 4u) {
            if      (row == col0)     p.x += 1.0f;
            else if (row == col0 + 1) p.y += 1.0f;
            else if (row == col0 + 2) p.z += 1.0f;
            else                      p.w += 1.0f;
        }
        // Pin the product in VGPRs. Without this, hipcc rematerializes after
        // the barrier (re-loads a,b + recomputes) -> 16 extra vmem/thread.
        // The empty volatile asm makes p's value opaque: it cannot be
        // recomputed, so it must stay live in registers (32 VGPRs, cheap).
        asm volatile("" : "+v"(p.x), "+v"(p.y), "+v"(p.z), "+v"(p.w));
        prod[i] = p;
        sum += (double)p.x + (double)p.y + (double)p.z + (double)p.w;
    }

    // wave-64 shuffle reduction
#pragma unroll
    for (int off = 32; off > 0; off >>= 1)
        sum += __shfl_down(sum, off, 64);

    __shared__ double wave_sums[BLOCK / 64];
    const int lane = tid & 63;
    const int wave = tid >> 6;
    if (lane == 0) wave_sums[wave] = sum;
    __syncthreads();

    // Every thread computes the total redundantly: saves the second barrier.
    const double total = wave_sums[0] + wave_sums[1] + wave_sums[2] + wave_sums[3];
    float r_inv = 1.0f / (float)total;
    if (isinf(r_inv)) r_inv = 0.0f;

#pragma unroll
    for (int i = 0; i < V4_PER_THREAD; ++i) {
        const int idx = tid + i * BLOCK;
        float4 p = prod[i];
        f32x4 v;
        v.x = p.x * r_inv;
        v.y = p.y * r_inv;
        v.z = p.z * r_inv;
        v.w = p.w * r_inv;
        // streamed-once output: bypass cache allocation
        __builtin_nontemporal_store(v, (f32x4*)(orow + (idx << 2)));
    }
}

extern "C" void kernel_launch(void* const* d_in, const int* in_sizes, int n_in,
                              void* d_out, int out_size, void* d_ws, size_t ws_size,
                              hipStream_t stream) {
    const float* a = (const float*)d_in[0];   // estimated_adj
    const float* b = (const float*)d_in[1];   // ori
    float* out = (float*)d_out;
    row_normalize_kernel<<<NDIM, BLOCK, 0, stream>>>(a, b, out);
}